// Round 1
// baseline (501.852 us; speedup 1.0000x reference)
//
#include <hip/hip_runtime.h>

typedef short bf16x8 __attribute__((ext_vector_type(8)));
typedef float f32x4 __attribute__((ext_vector_type(4)));

__device__ __forceinline__ ushort f2b(float f) {
  union { float f; unsigned u; } v; v.f = f;
  unsigned r = v.u + 0x7FFF + ((v.u >> 16) & 1);
  return (ushort)(r >> 16);
}
__device__ __forceinline__ float b2f(ushort u) {
  union { unsigned u; float f; } v; v.u = ((unsigned)u) << 16;
  return v.f;
}
__device__ __forceinline__ f32x4 mfma16(bf16x8 a, bf16x8 b, f32x4 c) {
  return __builtin_amdgcn_mfma_f32_16x16x32_bf16(a, b, c, 0, 0, 0);
}

#define GLD_LDS16(g, l) \
  __builtin_amdgcn_global_load_lds((const __attribute__((address_space(1))) void*)(g), \
                                   (__attribute__((address_space(3))) void*)(l), 16, 0, 0)

// ---------------- cast fp32 -> bf16 (vectorized) ----------------
__global__ __launch_bounds__(256) void cast_bf16(const float* __restrict__ in,
                                                 ushort* __restrict__ out, int n4) {
  int i = blockIdx.x * 256 + threadIdx.x;
  if (i >= n4) return;
  float4 f = ((const float4*)in)[i];
  ushort4 u;
  u.x = f2b(f.x); u.y = f2b(f.y); u.z = f2b(f.z); u.w = f2b(f.w);
  ((ushort4*)out)[i] = u;
}

// ---------------- RoPE tables ----------------
__global__ void rope_tables_k(float* __restrict__ cosT, float* __restrict__ sinT) {
  int s = blockIdx.x, i = threadIdx.x;  // 64 threads
  float inv = powf(10000.0f, -(float)i * (1.0f / 64.0f));
  float f = (float)s * inv;
  cosT[s * 64 + i] = cosf(f);
  sinT[s * 64 + i] = sinf(f);
}

// ---------------- GEMM: C[M][N] = A[M][K] * B[N][K]^T  (both row-major, K contiguous)
template <bool BF16OUT>
__global__ __launch_bounds__(256) void gemm_bt(const ushort* __restrict__ A,
                                               const ushort* __restrict__ B,
                                               void* __restrict__ Cout,
                                               int M, int N, int K) {
  __shared__ __align__(16) ushort As[128 * 32];
  __shared__ __align__(16) ushort Bs[128 * 32];
  const int t = threadIdx.x;
  const int lane = t & 63, w = t >> 6;
  const int wr = w >> 1, wc = w & 1;
  const int l15 = lane & 15, l4 = lane >> 4;
  const long m0 = (long)blockIdx.y * 128, n0 = (long)blockIdx.x * 128;
  f32x4 acc[4][4] = {};
  const int srow = t >> 2, scol = (t & 3) * 8;
  const ushort* ga = A + (m0 + srow) * K + scol;
  const ushort* gb = B + (n0 + srow) * K + scol;
  for (int k0 = 0; k0 < K; k0 += 32) {
    GLD_LDS16(ga,          &As[t * 8]);
    GLD_LDS16(ga + 64 * K, &As[2048 + t * 8]);
    GLD_LDS16(gb,          &Bs[t * 8]);
    GLD_LDS16(gb + 64 * K, &Bs[2048 + t * 8]);
    ga += 32; gb += 32;
    asm volatile("s_waitcnt vmcnt(0)" ::: "memory");
    __syncthreads();
    bf16x8 af[4], bfr[4];
#pragma unroll
    for (int i = 0; i < 4; ++i) {
      af[i]  = *(const bf16x8*)(&As[(wr * 64 + i * 16 + l15) * 32 + l4 * 8]);
      bfr[i] = *(const bf16x8*)(&Bs[(wc * 64 + i * 16 + l15) * 32 + l4 * 8]);
    }
#pragma unroll
    for (int i = 0; i < 4; ++i)
#pragma unroll
      for (int j = 0; j < 4; ++j)
        acc[i][j] = mfma16(af[i], bfr[j], acc[i][j]);
    __syncthreads();
  }
#pragma unroll
  for (int i = 0; i < 4; ++i) {
#pragma unroll
    for (int j = 0; j < 4; ++j) {
      long mrow = m0 + wr * 64 + i * 16 + l4 * 4;
      long ncol = n0 + wc * 64 + j * 16 + l15;
#pragma unroll
      for (int r = 0; r < 4; ++r) {
        if constexpr (BF16OUT)
          ((ushort*)Cout)[(mrow + r) * N + ncol] = f2b(acc[i][j][r]);
        else
          ((float*)Cout)[(mrow + r) * N + ncol] = acc[i][j][r];
      }
    }
  }
}

// ---------------- RMSnorm + RoPE + layout (q,k) / cast+transpose (v) ----------------
__global__ __launch_bounds__(256) void postproc_k(const ushort* __restrict__ qkvb,
                                                  const float* __restrict__ cosT,
                                                  const float* __restrict__ sinT,
                                                  ushort* __restrict__ qb,
                                                  ushort* __restrict__ kb,
                                                  ushort* __restrict__ vtb) {
  const int lane = threadIdx.x & 63;
  const int s = blockIdx.x * 4 + (threadIdx.x >> 6);
  const int h = blockIdx.y;  // 0..15 q heads, 16..19 k heads, 20..23 v heads
  const int colbase = (h < 16) ? h * 128 : (h < 20 ? 2048 + (h - 16) * 128
                                                   : 2560 + (h - 20) * 128);
  const ushort* row = qkvb + (long)s * 3072 + colbase;
  float x1 = b2f(row[lane]), x2 = b2f(row[lane + 64]);
  if (h >= 20) {  // V: cast + transpose to [kvh][128][S]
    int kvh = h - 20;
    vtb[(long)(kvh * 128 + lane) * 4096 + s]      = f2b(x1);
    vtb[(long)(kvh * 128 + lane + 64) * 4096 + s] = f2b(x2);
    return;
  }
  float ss = x1 * x1 + x2 * x2;
#pragma unroll
  for (int m = 1; m < 64; m <<= 1) ss += __shfl_xor(ss, m);
  float rn = rsqrtf(ss * (1.0f / 128.0f) + 1.1920929e-07f);
  float c = cosT[s * 64 + lane], sn = sinT[s * 64 + lane];
  float x1n = x1 * rn, x2n = x2 * rn;
  float o1 = x1n * c + x2n * sn;
  float o2 = x2n * c - x1n * sn;
  if (h < 16) {
    const float scq = 0.08838834764831845f;  // 1/sqrt(128) folded into q
    ushort* dst = qb + ((long)h * 4096 + s) * 128;
    dst[lane] = f2b(o1 * scq);
    dst[lane + 64] = f2b(o2 * scq);
  } else {
    ushort* dst = kb + ((long)(h - 16) * 4096 + s) * 128;
    dst[lane] = f2b(o1);
    dst[lane + 64] = f2b(o2);
  }
}

// ---------------- flash attention: 1 wave per (head, 16 q rows) ----------------
__global__ __launch_bounds__(64) void attn_k(const ushort* __restrict__ qb,
                                             const ushort* __restrict__ kb,
                                             const ushort* __restrict__ vtb,
                                             ushort* __restrict__ yb) {
  __shared__ __align__(16) ushort P[16 * 32];
  const int lane = threadIdx.x;
  const int l15 = lane & 15, l4 = lane >> 4;
  const int q0 = blockIdx.x * 16;
  const int h = blockIdx.y, kvh = h >> 2;
  const ushort* Qp = qb + ((long)h * 4096 + q0 + l15) * 128 + l4 * 8;
  bf16x8 qf[4];
#pragma unroll
  for (int c = 0; c < 4; ++c) qf[c] = *(const bf16x8*)(Qp + c * 32);
  f32x4 o[8] = {};
  float mrun[4], lrun[4];
#pragma unroll
  for (int r = 0; r < 4; ++r) { mrun[r] = -1e30f; lrun[r] = 0.0f; }
  int kstart = q0 - 1023; if (kstart < 0) kstart = 0;
  const int kb0 = kstart & ~31;
  const ushort* Kbase = kb + (long)kvh * 4096 * 128;
  const ushort* Vbase = vtb + (long)kvh * 128 * 4096;
  for (int kbs = kb0; kbs <= q0 + 15; kbs += 32) {
    f32x4 sc0 = {}, sc1 = {};
    {
      const ushort* Kp = Kbase + (long)(kbs + l15) * 128 + l4 * 8;
#pragma unroll
      for (int c = 0; c < 4; ++c) sc0 = mfma16(qf[c], *(const bf16x8*)(Kp + c * 32), sc0);
      Kp += 16 * 128;
#pragma unroll
      for (int c = 0; c < 4; ++c) sc1 = mfma16(qf[c], *(const bf16x8*)(Kp + c * 32), sc1);
    }
    float corr[4];
#pragma unroll
    for (int r = 0; r < 4; ++r) {
      const int q = q0 + l4 * 4 + r;
      const int k0i = kbs + l15, k1i = kbs + 16 + l15;
      float s0 = (k0i <= q && k0i > q - 1024) ? sc0[r] : -1e30f;
      float s1 = (k1i <= q && k1i > q - 1024) ? sc1[r] : -1e30f;
      float mx = fmaxf(s0, s1);
#pragma unroll
      for (int msk = 1; msk < 16; msk <<= 1) mx = fmaxf(mx, __shfl_xor(mx, msk));
      float mn = fmaxf(mrun[r], mx);
      corr[r] = __expf(mrun[r] - mn);
      float p0 = __expf(s0 - mn), p1 = __expf(s1 - mn);
      mrun[r] = mn;
      P[(l4 * 4 + r) * 32 + l15] = f2b(p0);
      P[(l4 * 4 + r) * 32 + 16 + l15] = f2b(p1);
      float ps = p0 + p1;
#pragma unroll
      for (int msk = 1; msk < 16; msk <<= 1) ps += __shfl_xor(ps, msk);
      lrun[r] = lrun[r] * corr[r] + ps;
    }
#pragma unroll
    for (int db = 0; db < 8; ++db)
#pragma unroll
      for (int r = 0; r < 4; ++r) o[db][r] *= corr[r];
    asm volatile("s_waitcnt lgkmcnt(0)" ::: "memory");
    bf16x8 pa = *(const bf16x8*)(&P[l15 * 32 + l4 * 8]);
#pragma unroll
    for (int db = 0; db < 8; ++db) {
      const ushort* Vp = Vbase + (long)(db * 16 + l15) * 4096 + kbs + l4 * 8;
      o[db] = mfma16(pa, *(const bf16x8*)Vp, o[db]);
    }
  }
  float inv[4];
#pragma unroll
  for (int r = 0; r < 4; ++r) inv[r] = 1.0f / lrun[r];
#pragma unroll
  for (int db = 0; db < 8; ++db)
#pragma unroll
    for (int r = 0; r < 4; ++r)
      yb[(long)(q0 + l4 * 4 + r) * 2048 + h * 128 + db * 16 + l15] =
          f2b(o[db][r] * inv[r]);
}

extern "C" void kernel_launch(void* const* d_in, const int* in_sizes, int n_in,
                              void* d_out, int out_size, void* d_ws, size_t ws_size,
                              hipStream_t stream) {
  (void)in_sizes; (void)n_in; (void)out_size; (void)ws_size;
  const float* x  = (const float*)d_in[0];
  const float* Wq = (const float*)d_in[1];
  const float* Wk = (const float*)d_in[2];
  const float* Wv = (const float*)d_in[3];
  const float* Wo = (const float*)d_in[4];
  const long S = 4096;
  ushort* ws   = (ushort*)d_ws;
  ushort* xb   = ws;                        // 4096*2048
  ushort* wqkv = xb + S * 2048;             // 3072*2048
  ushort* wob  = wqkv + 3072L * 2048;       // 2048*2048
  ushort* qkvb = wob + 2048L * 2048;        // 4096*3072
  ushort* qb   = qkvb + S * 3072;           // 16*4096*128
  ushort* kbuf = qb + S * 2048;             // 4*4096*128
  ushort* vtb  = kbuf + 4L * 4096 * 128;    // 4*128*4096
  ushort* yb   = vtb + 4L * 128 * 4096;     // 4096*2048
  float* cosT  = (float*)(yb + S * 2048);   // 4096*64
  float* sinT  = cosT + S * 64;             // 4096*64

  cast_bf16<<<dim3(8192), 256, 0, stream>>>(x, xb, (int)(S * 2048 / 4));
  cast_bf16<<<dim3(4096), 256, 0, stream>>>(Wq, wqkv, 2048 * 2048 / 4);
  cast_bf16<<<dim3(1024), 256, 0, stream>>>(Wk, wqkv + 2048L * 2048, 512 * 2048 / 4);
  cast_bf16<<<dim3(1024), 256, 0, stream>>>(Wv, wqkv + 2560L * 2048, 512 * 2048 / 4);
  cast_bf16<<<dim3(4096), 256, 0, stream>>>(Wo, wob, 2048 * 2048 / 4);

  gemm_bt<true><<<dim3(24, 32), 256, 0, stream>>>(xb, wqkv, qkvb, 4096, 3072, 2048);
  rope_tables_k<<<dim3(4096), 64, 0, stream>>>(cosT, sinT);
  postproc_k<<<dim3(1024, 24), 256, 0, stream>>>(qkvb, cosT, sinT, qb, kbuf, vtb);
  attn_k<<<dim3(256, 16), 64, 0, stream>>>(qb, kbuf, vtb, yb);
  gemm_bt<false><<<dim3(16, 32), 256, 0, stream>>>(yb, wob, d_out, 4096, 2048, 2048);
}

// Round 2
// 404.969 us; speedup vs baseline: 1.2392x; 1.2392x over previous
//
#include <hip/hip_runtime.h>

typedef short bf16x8 __attribute__((ext_vector_type(8)));
typedef float f32x4 __attribute__((ext_vector_type(4)));

__device__ __forceinline__ ushort f2b(float f) {
  union { float f; unsigned u; } v; v.f = f;
  unsigned r = v.u + 0x7FFF + ((v.u >> 16) & 1);
  return (ushort)(r >> 16);
}
__device__ __forceinline__ float b2f(ushort u) {
  union { unsigned u; float f; } v; v.u = ((unsigned)u) << 16;
  return v.f;
}
__device__ __forceinline__ unsigned pk2(float a, float b) {
  return (unsigned)f2b(a) | ((unsigned)f2b(b) << 16);
}
__device__ __forceinline__ f32x4 mfma16(bf16x8 a, bf16x8 b, f32x4 c) {
  return __builtin_amdgcn_mfma_f32_16x16x32_bf16(a, b, c, 0, 0, 0);
}

#define GLD_LDS16(g, l) \
  __builtin_amdgcn_global_load_lds((const __attribute__((address_space(1))) void*)(g), \
                                   (__attribute__((address_space(3))) void*)(l), 16, 0, 0)

// ---------------- cast fp32 -> bf16 (vectorized) ----------------
__global__ __launch_bounds__(256) void cast_bf16(const float* __restrict__ in,
                                                 ushort* __restrict__ out, int n4) {
  int i = blockIdx.x * 256 + threadIdx.x;
  if (i >= n4) return;
  float4 f = ((const float4*)in)[i];
  ushort4 u;
  u.x = f2b(f.x); u.y = f2b(f.y); u.z = f2b(f.z); u.w = f2b(f.w);
  ((ushort4*)out)[i] = u;
}

// ---------------- RoPE tables ----------------
__global__ void rope_tables_k(float* __restrict__ cosT, float* __restrict__ sinT) {
  int s = blockIdx.x, i = threadIdx.x;  // 64 threads
  float inv = powf(10000.0f, -(float)i * (1.0f / 64.0f));
  float f = (float)s * inv;
  cosT[s * 64 + i] = cosf(f);
  sinT[s * 64 + i] = sinf(f);
}

// ---------------- GEMM: C[M][N] = A[M][K] * B[N][K]^T  (both row-major, K contiguous)
template <bool BF16OUT>
__global__ __launch_bounds__(256) void gemm_bt(const ushort* __restrict__ A,
                                               const ushort* __restrict__ B,
                                               void* __restrict__ Cout,
                                               int M, int N, int K) {
  __shared__ __align__(16) ushort As[128 * 32];
  __shared__ __align__(16) ushort Bs[128 * 32];
  const int t = threadIdx.x;
  const int lane = t & 63, w = t >> 6;
  const int wr = w >> 1, wc = w & 1;
  const int l15 = lane & 15, l4 = lane >> 4;
  const long m0 = (long)blockIdx.y * 128, n0 = (long)blockIdx.x * 128;
  f32x4 acc[4][4] = {};
  const int srow = t >> 2, scol = (t & 3) * 8;
  const ushort* ga = A + (m0 + srow) * K + scol;
  const ushort* gb = B + (n0 + srow) * K + scol;
  for (int k0 = 0; k0 < K; k0 += 32) {
    GLD_LDS16(ga,          &As[t * 8]);
    GLD_LDS16(ga + 64 * K, &As[2048 + t * 8]);
    GLD_LDS16(gb,          &Bs[t * 8]);
    GLD_LDS16(gb + 64 * K, &Bs[2048 + t * 8]);
    ga += 32; gb += 32;
    asm volatile("s_waitcnt vmcnt(0)" ::: "memory");
    __syncthreads();
    bf16x8 af[4], bfr[4];
#pragma unroll
    for (int i = 0; i < 4; ++i) {
      af[i]  = *(const bf16x8*)(&As[(wr * 64 + i * 16 + l15) * 32 + l4 * 8]);
      bfr[i] = *(const bf16x8*)(&Bs[(wc * 64 + i * 16 + l15) * 32 + l4 * 8]);
    }
#pragma unroll
    for (int i = 0; i < 4; ++i)
#pragma unroll
      for (int j = 0; j < 4; ++j)
        acc[i][j] = mfma16(af[i], bfr[j], acc[i][j]);
    __syncthreads();
  }
#pragma unroll
  for (int i = 0; i < 4; ++i) {
#pragma unroll
    for (int j = 0; j < 4; ++j) {
      long mrow = m0 + wr * 64 + i * 16 + l4 * 4;
      long ncol = n0 + wc * 64 + j * 16 + l15;
#pragma unroll
      for (int r = 0; r < 4; ++r) {
        if constexpr (BF16OUT)
          ((ushort*)Cout)[(mrow + r) * N + ncol] = f2b(acc[i][j][r]);
        else
          ((float*)Cout)[(mrow + r) * N + ncol] = acc[i][j][r];
      }
    }
  }
}

// ---------------- RMSnorm + RoPE + layout (q,k) / cast+transpose (v) ----------------
__global__ __launch_bounds__(256) void postproc_k(const ushort* __restrict__ qkvb,
                                                  const float* __restrict__ cosT,
                                                  const float* __restrict__ sinT,
                                                  ushort* __restrict__ qb,
                                                  ushort* __restrict__ kb,
                                                  ushort* __restrict__ vtb) {
  const int lane = threadIdx.x & 63;
  const int s = blockIdx.x * 4 + (threadIdx.x >> 6);
  const int h = blockIdx.y;  // 0..15 q heads, 16..19 k heads, 20..23 v heads
  const int colbase = (h < 16) ? h * 128 : (h < 20 ? 2048 + (h - 16) * 128
                                                   : 2560 + (h - 20) * 128);
  const ushort* row = qkvb + (long)s * 3072 + colbase;
  float x1 = b2f(row[lane]), x2 = b2f(row[lane + 64]);
  if (h >= 20) {  // V: cast + transpose to [kvh][128][S]
    int kvh = h - 20;
    vtb[(long)(kvh * 128 + lane) * 4096 + s]      = f2b(x1);
    vtb[(long)(kvh * 128 + lane + 64) * 4096 + s] = f2b(x2);
    return;
  }
  float ss = x1 * x1 + x2 * x2;
#pragma unroll
  for (int m = 1; m < 64; m <<= 1) ss += __shfl_xor(ss, m);
  float rn = rsqrtf(ss * (1.0f / 128.0f) + 1.1920929e-07f);
  float c = cosT[s * 64 + lane], sn = sinT[s * 64 + lane];
  float x1n = x1 * rn, x2n = x2 * rn;
  float o1 = x1n * c + x2n * sn;
  float o2 = x2n * c - x1n * sn;
  if (h < 16) {
    const float scq = 0.08838834764831845f;  // 1/sqrt(128) folded into q
    ushort* dst = qb + ((long)h * 4096 + s) * 128;
    dst[lane] = f2b(o1 * scq);
    dst[lane + 64] = f2b(o2 * scq);
  } else {
    ushort* dst = kb + ((long)(h - 16) * 4096 + s) * 128;
    dst[lane] = f2b(o1);
    dst[lane + 64] = f2b(o2);
  }
}

// ---------------- flash attention v2: swapped QK^T, in-register softmax ----------------
// 4 waves/block, wave = 16 q rows. S^T = mfma(K, Q): lane q = l15, k = l4*4+r (+16).
// P^T goes through a 1KB XOR-swizzled LDS slice into PV's B-fragment.
// O^T = mfma(V^T, P^T): col = q = l15, row = d.
__global__ __launch_bounds__(256) void attn_k(const ushort* __restrict__ qb,
                                              const ushort* __restrict__ kb,
                                              const ushort* __restrict__ vtb,
                                              ushort* __restrict__ yb) {
  __shared__ __align__(16) ushort P[4][16 * 32];
  const int t = threadIdx.x;
  const int lane = t & 63, w = t >> 6;
  const int l15 = lane & 15, l4 = lane >> 4;
  const int q0 = ((int)gridDim.x - 1 - (int)blockIdx.x) * 64 + w * 16;  // heavy blocks first
  const int h = blockIdx.y, kvh = h >> 2;
  const int q = q0 + l15;  // this lane's q row (swapped layout: q = C column)

  const ushort* Qp = qb + ((long)h * 4096 + q) * 128 + l4 * 8;
  bf16x8 qf[4];
#pragma unroll
  for (int c = 0; c < 4; ++c) qf[c] = *(const bf16x8*)(Qp + c * 32);

  f32x4 o[8] = {};
  float mrun = -1e30f, lrun = 0.0f;

  ushort* Pw = P[w];
  unsigned* PwU = (unsigned*)Pw;
  // XOR-swizzled P offsets (all loop-invariant)
  const int sz2 = 4 * (l15 & 3);             // uint-granular swizzle
  const int wbase = l15 * 16;                // uint row base
  const int w00 = wbase + ((2 * l4 + 0) ^ sz2);
  const int w01 = wbase + ((2 * l4 + 1) ^ sz2);
  const int w10 = wbase + ((2 * l4 + 8) ^ sz2);
  const int w11 = wbase + ((2 * l4 + 9) ^ sz2);
  const ushort* rdP = &Pw[l15 * 32 + ((l4 * 8) ^ (8 * (l15 & 3)))];

  const ushort* Kbase = kb + (long)kvh * 4096 * 128;
  const ushort* Vbase = vtb + (long)kvh * 128 * 4096;

  int kstart = q0 - 1023; if (kstart < 0) kstart = 0;
  const int kb0 = kstart & ~31;
  for (int kbs = kb0; kbs <= q0 + 15; kbs += 32) {
    // ---- QK^T (swapped): sc0 = S^T[k=l4*4+r][q=l15], sc1 = +16 keys
    f32x4 sc0 = {}, sc1 = {};
    {
      const ushort* Kp = Kbase + (long)(kbs + l15) * 128 + l4 * 8;
#pragma unroll
      for (int c = 0; c < 4; ++c) sc0 = mfma16(*(const bf16x8*)(Kp + c * 32), qf[c], sc0);
      Kp += 16 * 128;
#pragma unroll
      for (int c = 0; c < 4; ++c) sc1 = mfma16(*(const bf16x8*)(Kp + c * 32), qf[c], sc1);
    }
    // ---- prefetch V^T fragments (latency hides under softmax VALU)
    bf16x8 vt[8];
#pragma unroll
    for (int db = 0; db < 8; ++db)
      vt[db] = *(const bf16x8*)(Vbase + (long)(db * 16 + l15) * 4096 + kbs + l4 * 8);

    // ---- mask + in-register softmax (single chain, 4 shuffles total)
    float s[8];
#pragma unroll
    for (int r = 0; r < 4; ++r) {
      const int k0i = kbs + l4 * 4 + r, k1i = k0i + 16;
      s[r]     = (k0i <= q && k0i > q - 1024) ? sc0[r] : -1e30f;
      s[r + 4] = (k1i <= q && k1i > q - 1024) ? sc1[r] : -1e30f;
    }
    float mx = s[0];
#pragma unroll
    for (int j = 1; j < 8; ++j) mx = fmaxf(mx, s[j]);
    mx = fmaxf(mx, __shfl_xor(mx, 16));
    mx = fmaxf(mx, __shfl_xor(mx, 32));

    float mn, corr;
    if (__all(mx <= mrun + 8.0f)) {      // T13 defer-max: skip O-rescale
      mn = mrun;
    } else {
      mn = fmaxf(mrun, mx);
      corr = __expf(mrun - mn);
      mrun = mn;
#pragma unroll
      for (int db = 0; db < 8; ++db)
#pragma unroll
        for (int r = 0; r < 4; ++r) o[db][r] *= corr;
      lrun *= corr;
    }
    float p[8];
#pragma unroll
    for (int j = 0; j < 8; ++j) p[j] = __expf(s[j] - mn);
    float ps = p[0];
#pragma unroll
    for (int j = 1; j < 8; ++j) ps += p[j];
    ps += __shfl_xor(ps, 16);
    ps += __shfl_xor(ps, 32);
    lrun += ps;

    // ---- P^T -> LDS (packed bf16 pairs, swizzled) -> B-fragment
    PwU[w00] = pk2(p[0], p[1]);
    PwU[w01] = pk2(p[2], p[3]);
    PwU[w10] = pk2(p[4], p[5]);
    PwU[w11] = pk2(p[6], p[7]);
    bf16x8 pb = *(const bf16x8*)rdP;

    // ---- PV (swapped): O^T[d][q] += V^T x P^T
#pragma unroll
    for (int db = 0; db < 8; ++db) o[db] = mfma16(vt[db], pb, o[db]);
  }

  const float inv = 1.0f / lrun;
#pragma unroll
  for (int db = 0; db < 8; ++db)
#pragma unroll
    for (int r = 0; r < 4; ++r)
      yb[(long)q * 2048 + h * 128 + db * 16 + l4 * 4 + r] = f2b(o[db][r] * inv);
}

extern "C" void kernel_launch(void* const* d_in, const int* in_sizes, int n_in,
                              void* d_out, int out_size, void* d_ws, size_t ws_size,
                              hipStream_t stream) {
  (void)in_sizes; (void)n_in; (void)out_size; (void)ws_size;
  const float* x  = (const float*)d_in[0];
  const float* Wq = (const float*)d_in[1];
  const float* Wk = (const float*)d_in[2];
  const float* Wv = (const float*)d_in[3];
  const float* Wo = (const float*)d_in[4];
  const long S = 4096;
  ushort* ws   = (ushort*)d_ws;
  ushort* xb   = ws;                        // 4096*2048
  ushort* wqkv = xb + S * 2048;             // 3072*2048
  ushort* wob  = wqkv + 3072L * 2048;       // 2048*2048
  ushort* qkvb = wob + 2048L * 2048;        // 4096*3072
  ushort* qb   = qkvb + S * 3072;           // 16*4096*128
  ushort* kbuf = qb + S * 2048;             // 4*4096*128
  ushort* vtb  = kbuf + 4L * 4096 * 128;    // 4*128*4096
  ushort* yb   = vtb + 4L * 128 * 4096;     // 4096*2048
  float* cosT  = (float*)(yb + S * 2048);   // 4096*64
  float* sinT  = cosT + S * 64;             // 4096*64

  cast_bf16<<<dim3(8192), 256, 0, stream>>>(x, xb, (int)(S * 2048 / 4));
  cast_bf16<<<dim3(4096), 256, 0, stream>>>(Wq, wqkv, 2048 * 2048 / 4);
  cast_bf16<<<dim3(1024), 256, 0, stream>>>(Wk, wqkv + 2048L * 2048, 512 * 2048 / 4);
  cast_bf16<<<dim3(1024), 256, 0, stream>>>(Wv, wqkv + 2560L * 2048, 512 * 2048 / 4);
  cast_bf16<<<dim3(4096), 256, 0, stream>>>(Wo, wob, 2048 * 2048 / 4);

  gemm_bt<true><<<dim3(24, 32), 256, 0, stream>>>(xb, wqkv, qkvb, 4096, 3072, 2048);
  rope_tables_k<<<dim3(4096), 64, 0, stream>>>(cosT, sinT);
  postproc_k<<<dim3(1024, 24), 256, 0, stream>>>(qkvb, cosT, sinT, qb, kbuf, vtb);
  attn_k<<<dim3(64, 16), 256, 0, stream>>>(qb, kbuf, vtb, yb);
  gemm_bt<false><<<dim3(16, 32), 256, 0, stream>>>(yb, wob, d_out, 4096, 2048, 2048);
}

// Round 3
// 238.583 us; speedup vs baseline: 2.1035x; 1.6974x over previous
//
#include <hip/hip_runtime.h>

typedef short bf16x8 __attribute__((ext_vector_type(8)));
typedef short short4v __attribute__((ext_vector_type(4)));
typedef float f32x4 __attribute__((ext_vector_type(4)));

__device__ __forceinline__ ushort f2b(float f) {
  union { float f; unsigned u; } v; v.f = f;
  unsigned r = v.u + 0x7FFF + ((v.u >> 16) & 1);
  return (ushort)(r >> 16);
}
__device__ __forceinline__ float b2f(ushort u) {
  union { unsigned u; float f; } v; v.u = ((unsigned)u) << 16;
  return v.f;
}
__device__ __forceinline__ unsigned cvtpk(float lo, float hi) {
  unsigned r;
  asm volatile("v_cvt_pk_bf16_f32 %0, %1, %2" : "=v"(r) : "v"(lo), "v"(hi));
  return r;
}
__device__ __forceinline__ f32x4 mfma16(bf16x8 a, bf16x8 b, f32x4 c) {
  return __builtin_amdgcn_mfma_f32_16x16x32_bf16(a, b, c, 0, 0, 0);
}

#define GLD_LDS16(g, l) \
  __builtin_amdgcn_global_load_lds((const __attribute__((address_space(1))) void*)(g), \
                                   (__attribute__((address_space(3))) void*)(l), 16, 0, 0)

// ---------------- cast fp32 -> bf16 (vectorized) ----------------
__global__ __launch_bounds__(256) void cast_bf16(const float* __restrict__ in,
                                                 ushort* __restrict__ out, int n4) {
  int i = blockIdx.x * 256 + threadIdx.x;
  if (i >= n4) return;
  float4 f = ((const float4*)in)[i];
  ushort4 u;
  u.x = f2b(f.x); u.y = f2b(f.y); u.z = f2b(f.z); u.w = f2b(f.w);
  ((ushort4*)out)[i] = u;
}

// ---------------- RoPE tables ----------------
__global__ void rope_tables_k(float* __restrict__ cosT, float* __restrict__ sinT) {
  int s = blockIdx.x, i = threadIdx.x;  // 64 threads
  float inv = powf(10000.0f, -(float)i * (1.0f / 64.0f));
  float f = (float)s * inv;
  cosT[s * 64 + i] = cosf(f);
  sinT[s * 64 + i] = sinf(f);
}

// ---------------- GEMM: C[M][N] = A[M][K] * B[N][K]^T ----------------
template <bool BF16OUT>
__global__ __launch_bounds__(256) void gemm_bt(const ushort* __restrict__ A,
                                               const ushort* __restrict__ B,
                                               void* __restrict__ Cout,
                                               int M, int N, int K) {
  __shared__ __align__(16) ushort As[128 * 32];
  __shared__ __align__(16) ushort Bs[128 * 32];
  const int t = threadIdx.x;
  const int lane = t & 63, w = t >> 6;
  const int wr = w >> 1, wc = w & 1;
  const int l15 = lane & 15, l4 = lane >> 4;
  const long m0 = (long)blockIdx.y * 128, n0 = (long)blockIdx.x * 128;
  f32x4 acc[4][4] = {};
  const int srow = t >> 2, scol = (t & 3) * 8;
  const ushort* ga = A + (m0 + srow) * K + scol;
  const ushort* gb = B + (n0 + srow) * K + scol;
  for (int k0 = 0; k0 < K; k0 += 32) {
    GLD_LDS16(ga,          &As[t * 8]);
    GLD_LDS16(ga + 64 * K, &As[2048 + t * 8]);
    GLD_LDS16(gb,          &Bs[t * 8]);
    GLD_LDS16(gb + 64 * K, &Bs[2048 + t * 8]);
    ga += 32; gb += 32;
    asm volatile("s_waitcnt vmcnt(0)" ::: "memory");
    __syncthreads();
    bf16x8 af[4], bfr[4];
#pragma unroll
    for (int i = 0; i < 4; ++i) {
      af[i]  = *(const bf16x8*)(&As[(wr * 64 + i * 16 + l15) * 32 + l4 * 8]);
      bfr[i] = *(const bf16x8*)(&Bs[(wc * 64 + i * 16 + l15) * 32 + l4 * 8]);
    }
#pragma unroll
    for (int i = 0; i < 4; ++i)
#pragma unroll
      for (int j = 0; j < 4; ++j)
        acc[i][j] = mfma16(af[i], bfr[j], acc[i][j]);
    __syncthreads();
  }
#pragma unroll
  for (int i = 0; i < 4; ++i) {
#pragma unroll
    for (int j = 0; j < 4; ++j) {
      long mrow = m0 + wr * 64 + i * 16 + l4 * 4;
      long ncol = n0 + wc * 64 + j * 16 + l15;
#pragma unroll
      for (int r = 0; r < 4; ++r) {
        if constexpr (BF16OUT)
          ((ushort*)Cout)[(mrow + r) * N + ncol] = f2b(acc[i][j][r]);
        else
          ((float*)Cout)[(mrow + r) * N + ncol] = acc[i][j][r];
      }
    }
  }
}

// ---------------- RMSnorm + RoPE + layout (q,k) / cast+transpose (v) ----------------
__global__ __launch_bounds__(256) void postproc_k(const ushort* __restrict__ qkvb,
                                                  const float* __restrict__ cosT,
                                                  const float* __restrict__ sinT,
                                                  ushort* __restrict__ qb,
                                                  ushort* __restrict__ kb,
                                                  ushort* __restrict__ vtb) {
  const int lane = threadIdx.x & 63;
  const int s = blockIdx.x * 4 + (threadIdx.x >> 6);
  const int h = blockIdx.y;
  const int colbase = (h < 16) ? h * 128 : (h < 20 ? 2048 + (h - 16) * 128
                                                   : 2560 + (h - 20) * 128);
  const ushort* row = qkvb + (long)s * 3072 + colbase;
  float x1 = b2f(row[lane]), x2 = b2f(row[lane + 64]);
  if (h >= 20) {  // V: cast + transpose to [kvh][128][S]
    int kvh = h - 20;
    vtb[(long)(kvh * 128 + lane) * 4096 + s]      = f2b(x1);
    vtb[(long)(kvh * 128 + lane + 64) * 4096 + s] = f2b(x2);
    return;
  }
  float ss = x1 * x1 + x2 * x2;
#pragma unroll
  for (int m = 1; m < 64; m <<= 1) ss += __shfl_xor(ss, m);
  float rn = rsqrtf(ss * (1.0f / 128.0f) + 1.1920929e-07f);
  float c = cosT[s * 64 + lane], sn = sinT[s * 64 + lane];
  float x1n = x1 * rn, x2n = x2 * rn;
  float o1 = x1n * c + x2n * sn;
  float o2 = x2n * c - x1n * sn;
  if (h < 16) {
    const float scq = 0.08838834764831845f;  // 1/sqrt(128) folded into q
    ushort* dst = qb + ((long)h * 4096 + s) * 128;
    dst[lane] = f2b(o1 * scq);
    dst[lane + 64] = f2b(o2 * scq);
  } else {
    ushort* dst = kb + ((long)(h - 16) * 4096 + s) * 128;
    dst[lane] = f2b(o1);
    dst[lane + 64] = f2b(o2);
  }
}

// ---------------- flash attention v3: LDS-staged K/V, dbuf, KVBLK=64 ----------------
// 8 waves/block, wave = 16 q rows (block = 128 rows, one head).
// K tile [64][128] bf16 + V^T tile [128][64] bf16 in LDS, 16B-chunk XOR swizzle
// (chunk ^= row&7) applied to the GLOBAL source (LDS linear; rule #21).
// Swapped QK^T (lane q = l15); P stays in registers via permuted-contraction PV.
__global__ __launch_bounds__(512) void attn_k(const ushort* __restrict__ qb,
                                              const ushort* __restrict__ kb,
                                              const ushort* __restrict__ vtb,
                                              ushort* __restrict__ yb) {
  __shared__ __align__(16) ushort lds[32768];  // 64KB: buf{0,1} x (K 8192us | V 8192us)
  const int t = threadIdx.x;
  const int lane = t & 63, w = t >> 6;
  const int l15 = lane & 15, l4 = lane >> 4;
  const int q0 = ((int)gridDim.x - 1 - (int)blockIdx.x) * 128;  // heavy blocks first
  const int h = blockIdx.y, kvh = h >> 2;
  const int qw = q0 + w * 16;
  const int q = qw + l15;
  const int swz = l15 & 7;

  const ushort* Qp = qb + ((long)h * 4096 + q) * 128 + l4 * 8;
  bf16x8 qf[4];
#pragma unroll
  for (int c = 0; c < 4; ++c) qf[c] = *(const bf16x8*)(Qp + c * 32);

  const ushort* Kg = kb + (long)kvh * 4096 * 128;
  const ushort* Vg = vtb + (long)kvh * 128 * 4096;

  int kb_lo = q0 - 1023; if (kb_lo < 0) kb_lo = 0; kb_lo &= ~63;
  const int nt = (q0 + 127 - kb_lo) / 64 + 1;

  // staging: 4 x global_load_lds(16B) per wave per tile (K:2, V:2)
  // K LDS ushort lbu -> row=lbu/128, chunk=(lbu/8)&15; source chunk ^= row&7
  // V LDS ushort lbu -> row=lbu/64,  chunk=(lbu/8)&7;  source chunk ^= row&7
  const int lbuA = (0 * 8 + w) * 512 + lane * 8;
  const int lbuB = (1 * 8 + w) * 512 + lane * 8;
  const int krA = lbuA >> 7, kcA = ((lbuA >> 3) & 15) ^ (krA & 7);
  const int krB = lbuB >> 7, kcB = ((lbuB >> 3) & 15) ^ (krB & 7);
  const int vrA = lbuA >> 6, vcA = ((lbuA >> 3) & 7) ^ (vrA & 7);
  const int vrB = lbuB >> 6, vcB = ((lbuB >> 3) & 7) ^ (vrB & 7);

#define STAGE(kbs, b)                                                        \
  do {                                                                       \
    ushort* Kl_ = &lds[(b) * 16384];                                         \
    ushort* Vl_ = &lds[(b) * 16384 + 8192];                                  \
    GLD_LDS16(Kg + (long)((kbs) + krA) * 128 + kcA * 8, Kl_ + lbuA);         \
    GLD_LDS16(Kg + (long)((kbs) + krB) * 128 + kcB * 8, Kl_ + lbuB);         \
    GLD_LDS16(Vg + (long)vrA * 4096 + (kbs) + vcA * 8, Vl_ + lbuA);          \
    GLD_LDS16(Vg + (long)vrB * 4096 + (kbs) + vcB * 8, Vl_ + lbuB);          \
  } while (0)

  f32x4 o[8] = {};
  float mrun = -1e30f, lrun = 0.0f;

  STAGE(kb_lo, 0);
  asm volatile("s_waitcnt vmcnt(0)" ::: "memory");
  __syncthreads();

  for (int ti = 0; ti < nt; ++ti) {
    const int kbs = kb_lo + ti * 64;
    const int cur = ti & 1;
    if (ti + 1 < nt) STAGE(kbs + 64, cur ^ 1);

    if (kbs + 63 >= qw - 1023 && kbs <= qw + 15) {  // wave-uniform active predicate
      const ushort* Kl = &lds[cur * 16384];
      const ushort* Vl = &lds[cur * 16384 + 8192];

      // ---- QK^T swapped: sc[st][r] = S^T[key=kbs+st*16+l4*4+r][q=l15]
      f32x4 sc[4];
#pragma unroll
      for (int st = 0; st < 4; ++st) {
        sc[st] = f32x4{0.f, 0.f, 0.f, 0.f};
        const ushort* kr = Kl + (st * 16 + l15) * 128;
#pragma unroll
        for (int c = 0; c < 4; ++c)
          sc[st] = mfma16(*(const bf16x8*)(kr + (((c * 4 + l4) ^ swz) * 8)), qf[c], sc[st]);
      }

      // ---- mask
      float s[16];
#pragma unroll
      for (int st = 0; st < 4; ++st)
#pragma unroll
        for (int r = 0; r < 4; ++r) {
          const int ki = kbs + st * 16 + l4 * 4 + r;
          s[st * 4 + r] = (ki <= q && ki > q - 1024) ? sc[st][r] : -1e30f;
        }

      // ---- max (tree + 2 shfl across l4 groups)
      float m0a = fmaxf(fmaxf(s[0], s[1]), fmaxf(s[2], s[3]));
      float m1a = fmaxf(fmaxf(s[4], s[5]), fmaxf(s[6], s[7]));
      float m2a = fmaxf(fmaxf(s[8], s[9]), fmaxf(s[10], s[11]));
      float m3a = fmaxf(fmaxf(s[12], s[13]), fmaxf(s[14], s[15]));
      float mx = fmaxf(fmaxf(m0a, m1a), fmaxf(m2a, m3a));
      mx = fmaxf(mx, __shfl_xor(mx, 16));
      mx = fmaxf(mx, __shfl_xor(mx, 32));

      float mn;
      if (__all(mx <= mrun + 8.0f)) {  // T13 defer-max
        mn = mrun;
      } else {
        mn = fmaxf(mrun, mx);
        const float corr = __expf(mrun - mn);
        mrun = mn;
#pragma unroll
        for (int db = 0; db < 8; ++db)
#pragma unroll
          for (int r = 0; r < 4; ++r) o[db][r] *= corr;
        lrun *= corr;
      }

      float p[16];
#pragma unroll
      for (int j = 0; j < 16; ++j) p[j] = __expf(s[j] - mn);
      float ps = ((p[0] + p[1]) + (p[2] + p[3])) + ((p[4] + p[5]) + (p[6] + p[7]));
      ps += ((p[8] + p[9]) + (p[10] + p[11])) + ((p[12] + p[13]) + (p[14] + p[15]));
      ps += __shfl_xor(ps, 16);
      ps += __shfl_xor(ps, 32);
      lrun += ps;

      // ---- pack P (permuted contraction: element m<4 -> key 4*l4+m, m>=4 -> 16+4*l4+m-4)
      union { unsigned u[4]; bf16x8 v; } pa, pb;
      pa.u[0] = cvtpk(p[0], p[1]);   pa.u[1] = cvtpk(p[2], p[3]);
      pa.u[2] = cvtpk(p[4], p[5]);   pa.u[3] = cvtpk(p[6], p[7]);
      pb.u[0] = cvtpk(p[8], p[9]);   pb.u[1] = cvtpk(p[10], p[11]);
      pb.u[2] = cvtpk(p[12], p[13]); pb.u[3] = cvtpk(p[14], p[15]);

      // ---- PV: O^T[d][q] += V^T x P^T  (A-fragments permuted to match)
      const int co = 4 * (l4 & 1);  // within-chunk ushort offset
      const int c0 = (l4 >> 1) ^ swz, c1 = (2 + (l4 >> 1)) ^ swz;
      const int c2 = (4 + (l4 >> 1)) ^ swz, c3 = (6 + (l4 >> 1)) ^ swz;
#pragma unroll
      for (int db = 0; db < 8; ++db) {
        const ushort* vr = Vl + (db * 16 + l15) * 64;
        short4v a0 = *(const short4v*)(vr + c0 * 8 + co);
        short4v a1 = *(const short4v*)(vr + c1 * 8 + co);
        bf16x8 va = __builtin_shufflevector(a0, a1, 0, 1, 2, 3, 4, 5, 6, 7);
        o[db] = mfma16(va, pa.v, o[db]);
        short4v b0 = *(const short4v*)(vr + c2 * 8 + co);
        short4v b1 = *(const short4v*)(vr + c3 * 8 + co);
        bf16x8 vb = __builtin_shufflevector(b0, b1, 0, 1, 2, 3, 4, 5, 6, 7);
        o[db] = mfma16(vb, pb.v, o[db]);
      }
    }
    __syncthreads();  // drains vmcnt(0): staged tile t+1 complete for all waves
  }

  const float inv = 1.0f / lrun;
#pragma unroll
  for (int db = 0; db < 8; ++db)
#pragma unroll
    for (int r = 0; r < 4; ++r)
      yb[(long)q * 2048 + h * 128 + db * 16 + l4 * 4 + r] = f2b(o[db][r] * inv);
}

extern "C" void kernel_launch(void* const* d_in, const int* in_sizes, int n_in,
                              void* d_out, int out_size, void* d_ws, size_t ws_size,
                              hipStream_t stream) {
  (void)in_sizes; (void)n_in; (void)out_size; (void)ws_size;
  const float* x  = (const float*)d_in[0];
  const float* Wq = (const float*)d_in[1];
  const float* Wk = (const float*)d_in[2];
  const float* Wv = (const float*)d_in[3];
  const float* Wo = (const float*)d_in[4];
  const long S = 4096;
  ushort* ws   = (ushort*)d_ws;
  ushort* xb   = ws;                        // 4096*2048
  ushort* wqkv = xb + S * 2048;             // 3072*2048
  ushort* wob  = wqkv + 3072L * 2048;       // 2048*2048
  ushort* qkvb = wob + 2048L * 2048;        // 4096*3072
  ushort* qb   = qkvb + S * 3072;           // 16*4096*128
  ushort* kbuf = qb + S * 2048;             // 4*4096*128
  ushort* vtb  = kbuf + 4L * 4096 * 128;    // 4*128*4096
  ushort* yb   = vtb + 4L * 128 * 4096;     // 4096*2048
  float* cosT  = (float*)(yb + S * 2048);   // 4096*64
  float* sinT  = cosT + S * 64;             // 4096*64

  cast_bf16<<<dim3(8192), 256, 0, stream>>>(x, xb, (int)(S * 2048 / 4));
  cast_bf16<<<dim3(4096), 256, 0, stream>>>(Wq, wqkv, 2048 * 2048 / 4);
  cast_bf16<<<dim3(1024), 256, 0, stream>>>(Wk, wqkv + 2048L * 2048, 512 * 2048 / 4);
  cast_bf16<<<dim3(1024), 256, 0, stream>>>(Wv, wqkv + 2560L * 2048, 512 * 2048 / 4);
  cast_bf16<<<dim3(4096), 256, 0, stream>>>(Wo, wob, 2048 * 2048 / 4);

  gemm_bt<true><<<dim3(24, 32), 256, 0, stream>>>(xb, wqkv, qkvb, 4096, 3072, 2048);
  rope_tables_k<<<dim3(4096), 64, 0, stream>>>(cosT, sinT);
  postproc_k<<<dim3(1024, 24), 256, 0, stream>>>(qkvb, cosT, sinT, qb, kbuf, vtb);
  attn_k<<<dim3(32, 16), 512, 0, stream>>>(qb, kbuf, vtb, yb);
  gemm_bt<false><<<dim3(16, 32), 256, 0, stream>>>(yb, wob, d_out, 4096, 2048, 2048);
}

// Round 4
// 223.784 us; speedup vs baseline: 2.2426x; 1.0661x over previous
//
#include <hip/hip_runtime.h>

typedef short bf16x8 __attribute__((ext_vector_type(8)));
typedef short short4v __attribute__((ext_vector_type(4)));
typedef float f32x4 __attribute__((ext_vector_type(4)));

__device__ __forceinline__ ushort f2b(float f) {
  union { float f; unsigned u; } v; v.f = f;
  unsigned r = v.u + 0x7FFF + ((v.u >> 16) & 1);
  return (ushort)(r >> 16);
}
__device__ __forceinline__ float b2f(ushort u) {
  union { unsigned u; float f; } v; v.u = ((unsigned)u) << 16;
  return v.f;
}
__device__ __forceinline__ unsigned cvtpk(float lo, float hi) {
  unsigned r;
  asm volatile("v_cvt_pk_bf16_f32 %0, %1, %2" : "=v"(r) : "v"(lo), "v"(hi));
  return r;
}
__device__ __forceinline__ f32x4 mfma16(bf16x8 a, bf16x8 b, f32x4 c) {
  return __builtin_amdgcn_mfma_f32_16x16x32_bf16(a, b, c, 0, 0, 0);
}

#define GLD_LDS16(g, l) \
  __builtin_amdgcn_global_load_lds((const __attribute__((address_space(1))) void*)(g), \
                                   (__attribute__((address_space(3))) void*)(l), 16, 0, 0)

// ---------------- cast fp32 -> bf16 (vectorized) ----------------
__global__ __launch_bounds__(256) void cast_bf16(const float* __restrict__ in,
                                                 ushort* __restrict__ out, int n4) {
  int i = blockIdx.x * 256 + threadIdx.x;
  if (i >= n4) return;
  float4 f = ((const float4*)in)[i];
  ushort4 u;
  u.x = f2b(f.x); u.y = f2b(f.y); u.z = f2b(f.z); u.w = f2b(f.w);
  ((ushort4*)out)[i] = u;
}

// ---------------- RoPE tables ----------------
__global__ void rope_tables_k(float* __restrict__ cosT, float* __restrict__ sinT) {
  int s = blockIdx.x, i = threadIdx.x;  // 64 threads
  float inv = powf(10000.0f, -(float)i * (1.0f / 64.0f));
  float f = (float)s * inv;
  cosT[s * 64 + i] = cosf(f);
  sinT[s * 64 + i] = sinf(f);
}

// ---------------- pipelined GEMM: C[M][N] = A[M][K]*B[N][K]^T ----------------
// BM=256 BN=128 BK=64, 8 waves (4M x 2N), 512 thr. LDS 128KB:
//   A: 3-slot rotation (staged 2 tiles ahead), B: 2-slot (1 ahead, issued early).
// Counted vmcnt(4) per K-tile; raw s_barrier (no vmcnt(0) drain in loop).
// LDS layout: [16x32]-bf16 subtiles, XOR swizzle us ^= ((us>>6)&3)<<3 (involution),
// applied to global SOURCE at stage + read address (rule #21 both-sides).
template <bool BF16OUT>
__global__ __launch_bounds__(512) void gemm256(const ushort* __restrict__ A,
                                               const ushort* __restrict__ B,
                                               void* __restrict__ Cout,
                                               int M, int N, int K) {
  __shared__ __align__(16) ushort lds[65536];  // A: 3*16384 @0 ; B: 2*8192 @49152
  const int t = threadIdx.x;
  const int lane = t & 63, w = t >> 6;
  const int wr = w & 3, wc = w >> 2;
  const int l15 = lane & 15, l4 = lane >> 4;
  const int nbn = N >> 7;
  const long m0 = (long)(blockIdx.x / nbn) * 256;
  const long n0 = (long)(blockIdx.x % nbn) * 128;
  const int nk = K >> 6;

  // read-side swizzled fragment offset (lane-constant)
  const int rd0 = l15 * 32 + l4 * 8;
  const int rdoff = rd0 ^ ((((rd0 >> 6) & 3)) << 3);

  // staging source coords: unswizzle the linear LDS dest address
  int arow[4], acol[4], brow[2], bcol[2];
#pragma unroll
  for (int r = 0; r < 4; ++r) {
    int us = r * 4096 + t * 8;
    int uu = us ^ (((us >> 6) & 3) << 3);
    int sub = uu >> 9;
    arow[r] = (sub >> 1) * 16 + ((uu >> 5) & 15);
    acol[r] = (sub & 1) * 32 + (uu & 31);
    if (r < 2) { brow[r] = arow[r]; bcol[r] = acol[r]; }
  }

#define STAGE_A(kk, slot)                                                      \
  do {                                                                         \
    _Pragma("unroll") for (int r = 0; r < 4; ++r)                              \
        GLD_LDS16(A + (m0 + arow[r]) * K + (kk) + acol[r],                     \
                  &lds[(slot) * 16384 + r * 4096 + t * 8]);                    \
  } while (0)
#define STAGE_B(kk, slot)                                                      \
  do {                                                                         \
    _Pragma("unroll") for (int r = 0; r < 2; ++r)                              \
        GLD_LDS16(B + (n0 + brow[r]) * K + (kk) + bcol[r],                     \
                  &lds[49152 + (slot) * 8192 + r * 4096 + t * 8]);             \
  } while (0)

  f32x4 acc[4][4] = {};

  // prologue: order matters for vmcnt accounting: [A0, B0, A1]
  STAGE_A(0, 0);
  STAGE_B(0, 0);
  STAGE_A(64, 1);

  for (int j = 0; j < nk; ++j) {
    const int sa = j % 3, sb = j & 1;
    asm volatile("s_waitcnt vmcnt(4)" ::: "memory");  // tile j resident; A(j+1) in flight
    __builtin_amdgcn_s_barrier();

    // ---- phase 0: stage B(j+1); read all B frags + A i=0,1; MFMA i=0,1
    {
      int kn = j + 1; if (kn > nk - 1) kn = nk - 1;
      STAGE_B(kn * 64, (j + 1) & 1);
    }
    bf16x8 bfrag[4][2], afrag[2][2];
#pragma unroll
    for (int n = 0; n < 4; ++n)
#pragma unroll
      for (int ks = 0; ks < 2; ++ks)
        bfrag[n][ks] = *(const bf16x8*)(&lds[49152 + sb * 8192 +
                                             ((wc * 4 + n) * 2 + ks) * 512 + rdoff]);
#pragma unroll
    for (int i = 0; i < 2; ++i)
#pragma unroll
      for (int ks = 0; ks < 2; ++ks)
        afrag[i][ks] = *(const bf16x8*)(&lds[sa * 16384 +
                                             ((wr * 4 + i) * 2 + ks) * 512 + rdoff]);
    __builtin_amdgcn_s_setprio(1);
#pragma unroll
    for (int i = 0; i < 2; ++i)
#pragma unroll
      for (int n = 0; n < 4; ++n)
#pragma unroll
        for (int ks = 0; ks < 2; ++ks)
          acc[i][n] = mfma16(afrag[i][ks], bfrag[n][ks], acc[i][n]);
    __builtin_amdgcn_s_setprio(0);
    __builtin_amdgcn_s_barrier();

    // ---- phase 1: stage A(j+2); read A i=2,3; MFMA i=2,3
    {
      int kn = j + 2; if (kn > nk - 1) kn = nk - 1;
      STAGE_A(kn * 64, (j + 2) % 3);
    }
    bf16x8 afrag1[2][2];
#pragma unroll
    for (int i = 0; i < 2; ++i)
#pragma unroll
      for (int ks = 0; ks < 2; ++ks)
        afrag1[i][ks] = *(const bf16x8*)(&lds[sa * 16384 +
                                              ((wr * 4 + i + 2) * 2 + ks) * 512 + rdoff]);
    __builtin_amdgcn_s_setprio(1);
#pragma unroll
    for (int i = 0; i < 2; ++i)
#pragma unroll
      for (int n = 0; n < 4; ++n)
#pragma unroll
        for (int ks = 0; ks < 2; ++ks)
          acc[i + 2][n] = mfma16(afrag1[i][ks], bfrag[n][ks], acc[i + 2][n]);
    __builtin_amdgcn_s_setprio(0);
  }
  asm volatile("s_waitcnt vmcnt(0)" ::: "memory");

#pragma unroll
  for (int i = 0; i < 4; ++i) {
#pragma unroll
    for (int n = 0; n < 4; ++n) {
      long mrow = m0 + wr * 64 + i * 16 + l4 * 4;
      long ncol = n0 + wc * 64 + n * 16 + l15;
#pragma unroll
      for (int r = 0; r < 4; ++r) {
        if constexpr (BF16OUT)
          ((ushort*)Cout)[(mrow + r) * N + ncol] = f2b(acc[i][n][r]);
        else
          ((float*)Cout)[(mrow + r) * N + ncol] = acc[i][n][r];
      }
    }
  }
#undef STAGE_A
#undef STAGE_B
}

// ---------------- RMSnorm + RoPE + layout (q,k) / cast+transpose (v) ----------------
__global__ __launch_bounds__(256) void postproc_k(const ushort* __restrict__ qkvb,
                                                  const float* __restrict__ cosT,
                                                  const float* __restrict__ sinT,
                                                  ushort* __restrict__ qb,
                                                  ushort* __restrict__ kb,
                                                  ushort* __restrict__ vtb) {
  const int lane = threadIdx.x & 63;
  const int s = blockIdx.x * 4 + (threadIdx.x >> 6);
  const int h = blockIdx.y;
  const int colbase = (h < 16) ? h * 128 : (h < 20 ? 2048 + (h - 16) * 128
                                                   : 2560 + (h - 20) * 128);
  const ushort* row = qkvb + (long)s * 3072 + colbase;
  float x1 = b2f(row[lane]), x2 = b2f(row[lane + 64]);
  if (h >= 20) {  // V: cast + transpose to [kvh][128][S]
    int kvh = h - 20;
    vtb[(long)(kvh * 128 + lane) * 4096 + s]      = f2b(x1);
    vtb[(long)(kvh * 128 + lane + 64) * 4096 + s] = f2b(x2);
    return;
  }
  float ss = x1 * x1 + x2 * x2;
#pragma unroll
  for (int m = 1; m < 64; m <<= 1) ss += __shfl_xor(ss, m);
  float rn = rsqrtf(ss * (1.0f / 128.0f) + 1.1920929e-07f);
  float c = cosT[s * 64 + lane], sn = sinT[s * 64 + lane];
  float x1n = x1 * rn, x2n = x2 * rn;
  float o1 = x1n * c + x2n * sn;
  float o2 = x2n * c - x1n * sn;
  if (h < 16) {
    const float scq = 0.08838834764831845f;  // 1/sqrt(128) folded into q
    ushort* dst = qb + ((long)h * 4096 + s) * 128;
    dst[lane] = f2b(o1 * scq);
    dst[lane + 64] = f2b(o2 * scq);
  } else {
    ushort* dst = kb + ((long)(h - 16) * 4096 + s) * 128;
    dst[lane] = f2b(o1);
    dst[lane + 64] = f2b(o2);
  }
}

// ---------------- flash attention: LDS-staged K/V, dbuf, KVBLK=64 ----------------
__global__ __launch_bounds__(512) void attn_k(const ushort* __restrict__ qb,
                                              const ushort* __restrict__ kb,
                                              const ushort* __restrict__ vtb,
                                              ushort* __restrict__ yb) {
  __shared__ __align__(16) ushort lds[32768];  // 64KB: buf{0,1} x (K 8192us | V 8192us)
  const int t = threadIdx.x;
  const int lane = t & 63, w = t >> 6;
  const int l15 = lane & 15, l4 = lane >> 4;
  const int q0 = ((int)gridDim.x - 1 - (int)blockIdx.x) * 128;  // heavy blocks first
  const int h = blockIdx.y, kvh = h >> 2;
  const int qw = q0 + w * 16;
  const int q = qw + l15;
  const int swz = l15 & 7;

  const ushort* Qp = qb + ((long)h * 4096 + q) * 128 + l4 * 8;
  bf16x8 qf[4];
#pragma unroll
  for (int c = 0; c < 4; ++c) qf[c] = *(const bf16x8*)(Qp + c * 32);

  const ushort* Kg = kb + (long)kvh * 4096 * 128;
  const ushort* Vg = vtb + (long)kvh * 128 * 4096;

  int kb_lo = q0 - 1023; if (kb_lo < 0) kb_lo = 0; kb_lo &= ~63;
  const int nt = (q0 + 127 - kb_lo) / 64 + 1;

  const int lbuA = (0 * 8 + w) * 512 + lane * 8;
  const int lbuB = (1 * 8 + w) * 512 + lane * 8;
  const int krA = lbuA >> 7, kcA = ((lbuA >> 3) & 15) ^ (krA & 7);
  const int krB = lbuB >> 7, kcB = ((lbuB >> 3) & 15) ^ (krB & 7);
  const int vrA = lbuA >> 6, vcA = ((lbuA >> 3) & 7) ^ (vrA & 7);
  const int vrB = lbuB >> 6, vcB = ((lbuB >> 3) & 7) ^ (vrB & 7);

#define STAGE(kbs, b)                                                        \
  do {                                                                       \
    ushort* Kl_ = &lds[(b) * 16384];                                         \
    ushort* Vl_ = &lds[(b) * 16384 + 8192];                                  \
    GLD_LDS16(Kg + (long)((kbs) + krA) * 128 + kcA * 8, Kl_ + lbuA);         \
    GLD_LDS16(Kg + (long)((kbs) + krB) * 128 + kcB * 8, Kl_ + lbuB);         \
    GLD_LDS16(Vg + (long)vrA * 4096 + (kbs) + vcA * 8, Vl_ + lbuA);          \
    GLD_LDS16(Vg + (long)vrB * 4096 + (kbs) + vcB * 8, Vl_ + lbuB);          \
  } while (0)

  f32x4 o[8] = {};
  float mrun = -1e30f, lrun = 0.0f;

  STAGE(kb_lo, 0);
  asm volatile("s_waitcnt vmcnt(0)" ::: "memory");
  __syncthreads();

  for (int ti = 0; ti < nt; ++ti) {
    const int kbs = kb_lo + ti * 64;
    const int cur = ti & 1;
    if (ti + 1 < nt) STAGE(kbs + 64, cur ^ 1);

    if (kbs + 63 >= qw - 1023 && kbs <= qw + 15) {
      const ushort* Kl = &lds[cur * 16384];
      const ushort* Vl = &lds[cur * 16384 + 8192];

      f32x4 sc[4];
#pragma unroll
      for (int st = 0; st < 4; ++st) {
        sc[st] = f32x4{0.f, 0.f, 0.f, 0.f};
        const ushort* kr = Kl + (st * 16 + l15) * 128;
#pragma unroll
        for (int c = 0; c < 4; ++c)
          sc[st] = mfma16(*(const bf16x8*)(kr + (((c * 4 + l4) ^ swz) * 8)), qf[c], sc[st]);
      }

      float s[16];
#pragma unroll
      for (int st = 0; st < 4; ++st)
#pragma unroll
        for (int r = 0; r < 4; ++r) {
          const int ki = kbs + st * 16 + l4 * 4 + r;
          s[st * 4 + r] = (ki <= q && ki > q - 1024) ? sc[st][r] : -1e30f;
        }

      float m0a = fmaxf(fmaxf(s[0], s[1]), fmaxf(s[2], s[3]));
      float m1a = fmaxf(fmaxf(s[4], s[5]), fmaxf(s[6], s[7]));
      float m2a = fmaxf(fmaxf(s[8], s[9]), fmaxf(s[10], s[11]));
      float m3a = fmaxf(fmaxf(s[12], s[13]), fmaxf(s[14], s[15]));
      float mx = fmaxf(fmaxf(m0a, m1a), fmaxf(m2a, m3a));
      mx = fmaxf(mx, __shfl_xor(mx, 16));
      mx = fmaxf(mx, __shfl_xor(mx, 32));

      float mn;
      if (__all(mx <= mrun + 8.0f)) {  // T13 defer-max
        mn = mrun;
      } else {
        mn = fmaxf(mrun, mx);
        const float corr = __expf(mrun - mn);
        mrun = mn;
#pragma unroll
        for (int db = 0; db < 8; ++db)
#pragma unroll
          for (int r = 0; r < 4; ++r) o[db][r] *= corr;
        lrun *= corr;
      }

      float p[16];
#pragma unroll
      for (int j = 0; j < 16; ++j) p[j] = __expf(s[j] - mn);
      float ps = ((p[0] + p[1]) + (p[2] + p[3])) + ((p[4] + p[5]) + (p[6] + p[7]));
      ps += ((p[8] + p[9]) + (p[10] + p[11])) + ((p[12] + p[13]) + (p[14] + p[15]));
      ps += __shfl_xor(ps, 16);
      ps += __shfl_xor(ps, 32);
      lrun += ps;

      union { unsigned u[4]; bf16x8 v; } pa, pb;
      pa.u[0] = cvtpk(p[0], p[1]);   pa.u[1] = cvtpk(p[2], p[3]);
      pa.u[2] = cvtpk(p[4], p[5]);   pa.u[3] = cvtpk(p[6], p[7]);
      pb.u[0] = cvtpk(p[8], p[9]);   pb.u[1] = cvtpk(p[10], p[11]);
      pb.u[2] = cvtpk(p[12], p[13]); pb.u[3] = cvtpk(p[14], p[15]);

      const int co = 4 * (l4 & 1);
      const int c0 = (l4 >> 1) ^ swz, c1 = (2 + (l4 >> 1)) ^ swz;
      const int c2 = (4 + (l4 >> 1)) ^ swz, c3 = (6 + (l4 >> 1)) ^ swz;
#pragma unroll
      for (int db = 0; db < 8; ++db) {
        const ushort* vr = Vl + (db * 16 + l15) * 64;
        short4v a0 = *(const short4v*)(vr + c0 * 8 + co);
        short4v a1 = *(const short4v*)(vr + c1 * 8 + co);
        bf16x8 va = __builtin_shufflevector(a0, a1, 0, 1, 2, 3, 4, 5, 6, 7);
        o[db] = mfma16(va, pa.v, o[db]);
        short4v b0 = *(const short4v*)(vr + c2 * 8 + co);
        short4v b1 = *(const short4v*)(vr + c3 * 8 + co);
        bf16x8 vb = __builtin_shufflevector(b0, b1, 0, 1, 2, 3, 4, 5, 6, 7);
        o[db] = mfma16(vb, pb.v, o[db]);
      }
    }
    __syncthreads();
  }

  const float inv = 1.0f / lrun;
#pragma unroll
  for (int db = 0; db < 8; ++db)
#pragma unroll
    for (int r = 0; r < 4; ++r)
      yb[(long)q * 2048 + h * 128 + db * 16 + l4 * 4 + r] = f2b(o[db][r] * inv);
}

extern "C" void kernel_launch(void* const* d_in, const int* in_sizes, int n_in,
                              void* d_out, int out_size, void* d_ws, size_t ws_size,
                              hipStream_t stream) {
  (void)in_sizes; (void)n_in; (void)out_size; (void)ws_size;
  const float* x  = (const float*)d_in[0];
  const float* Wq = (const float*)d_in[1];
  const float* Wk = (const float*)d_in[2];
  const float* Wv = (const float*)d_in[3];
  const float* Wo = (const float*)d_in[4];
  const long S = 4096;
  ushort* ws   = (ushort*)d_ws;
  ushort* xb   = ws;                        // 4096*2048
  ushort* wqkv = xb + S * 2048;             // 3072*2048
  ushort* wob  = wqkv + 3072L * 2048;       // 2048*2048
  ushort* qkvb = wob + 2048L * 2048;        // 4096*3072
  ushort* qb   = qkvb + S * 3072;           // 16*4096*128
  ushort* kbuf = qb + S * 2048;             // 4*4096*128
  ushort* vtb  = kbuf + 4L * 4096 * 128;    // 4*128*4096
  ushort* yb   = vtb + 4L * 128 * 4096;     // 4096*2048
  float* cosT  = (float*)(yb + S * 2048);   // 4096*64
  float* sinT  = cosT + S * 64;             // 4096*64

  cast_bf16<<<dim3(8192), 256, 0, stream>>>(x, xb, (int)(S * 2048 / 4));
  cast_bf16<<<dim3(4096), 256, 0, stream>>>(Wq, wqkv, 2048 * 2048 / 4);
  cast_bf16<<<dim3(1024), 256, 0, stream>>>(Wk, wqkv + 2048L * 2048, 512 * 2048 / 4);
  cast_bf16<<<dim3(1024), 256, 0, stream>>>(Wv, wqkv + 2560L * 2048, 512 * 2048 / 4);
  cast_bf16<<<dim3(4096), 256, 0, stream>>>(Wo, wob, 2048 * 2048 / 4);

  gemm256<true><<<dim3(16 * 24), 512, 0, stream>>>(xb, wqkv, qkvb, 4096, 3072, 2048);
  rope_tables_k<<<dim3(4096), 64, 0, stream>>>(cosT, sinT);
  postproc_k<<<dim3(1024, 24), 256, 0, stream>>>(qkvb, cosT, sinT, qb, kbuf, vtb);
  attn_k<<<dim3(32, 16), 512, 0, stream>>>(qb, kbuf, vtb, yb);
  gemm256<false><<<dim3(16 * 16), 512, 0, stream>>>(yb, wob, d_out, 4096, 2048, 2048);
}